// Round 1
// baseline (46.702 us; speedup 1.0000x reference)
//
#include <hip/hip_runtime.h>

// VectorQuantizer: N=65536 rows (B*H*W), K=1024 codes, D=16, fp32 in/out.
// Out layout (fp32): z_q_st [0,1048576) | loss [1048576] | indices-as-float [1048577,1114113)

constexpr int BLOCK = 256;
constexpr int NROWS = 65536;
constexpr int K = 1024;
constexpr int RPB = 128;                 // rows per block (64 lanes x 2 rows)
constexpr int NBLK = NROWS / RPB;        // 512 blocks
constexpr int OFF_LOSS = 1048576;
constexpr int OFF_IDX  = 1048577;

// numpy pairwise_sum (n=16, unrolled-by-8 scalar path) of squares.
// squares rounded first (no fma contraction), then r[j]=s[j]+s[j+8],
// res = ((r0+r1)+(r2+r3)) + ((r4+r5)+(r6+r7))  -- bitwise-matches np.sum(x**2, axis=1).
__device__ __forceinline__ float np_sumsq16(const float* a) {
  float s[16];
#pragma unroll
  for (int j = 0; j < 16; ++j) s[j] = __fmul_rn(a[j], a[j]);
  float r[8];
#pragma unroll
  for (int j = 0; j < 8; ++j) r[j] = __fadd_rn(s[j], s[j + 8]);
  const float t0 = __fadd_rn(r[0], r[1]);
  const float t1 = __fadd_rn(r[2], r[3]);
  const float t2 = __fadd_rn(r[4], r[5]);
  const float t3 = __fadd_rn(r[6], r[7]);
  return __fadd_rn(__fadd_rn(t0, t1), __fadd_rn(t2, t3));
}

// dist = R( R(z2 + e2k) - 2*dot ) : matches np's  (z2 + e2) - 2*Z@E.T  rounding structure.
__device__ __forceinline__ void dist_update(const float4 zr[4],
                                            const float4& e0, const float4& e1,
                                            const float4& e2, const float4& e3,
                                            float z2, float e2k, int k,
                                            float& best, int& bidx) {
  float c0 = zr[0].x * e0.x; c0 = fmaf(zr[0].y, e0.y, c0); c0 = fmaf(zr[0].z, e0.z, c0); c0 = fmaf(zr[0].w, e0.w, c0);
  float c1 = zr[1].x * e1.x; c1 = fmaf(zr[1].y, e1.y, c1); c1 = fmaf(zr[1].z, e1.z, c1); c1 = fmaf(zr[1].w, e1.w, c1);
  float c2 = zr[2].x * e2.x; c2 = fmaf(zr[2].y, e2.y, c2); c2 = fmaf(zr[2].z, e2.z, c2); c2 = fmaf(zr[2].w, e2.w, c2);
  float c3 = zr[3].x * e3.x; c3 = fmaf(zr[3].y, e3.y, c3); c3 = fmaf(zr[3].z, e3.z, c3); c3 = fmaf(zr[3].w, e3.w, c3);
  const float dot  = __fadd_rn(__fadd_rn(c0, c1), __fadd_rn(c2, c3));
  const float dist = __fmaf_rn(-2.0f, dot, __fadd_rn(z2, e2k));
  if (dist < best) { best = dist; bidx = k; }   // strict '<' keeps FIRST index (np.argmin)
}

__device__ __forceinline__ float finalize_row(const float4 zr[4], const float4* se,
                                              int idx, int row, float* __restrict__ out) {
  float4 e[4];
#pragma unroll
  for (int i = 0; i < 4; ++i) e[i] = se[idx * 4 + i];
  const float* zz = reinterpret_cast<const float*>(zr);
  const float* ee = reinterpret_cast<const float*>(e);
  float4 ov[4];
  float* o = reinterpret_cast<float*>(ov);
  float lsum = 0.f;
#pragma unroll
  for (int j = 0; j < 16; ++j) {
    const float d = __fsub_rn(ee[j], zz[j]);   // z_q - z
    lsum = fmaf(d, d, lsum);                   // loss partial (order-insensitive vs threshold)
    o[j] = __fadd_rn(zz[j], d);                // z + (z_q - z)  (matches np z_q_st rounding)
  }
  float4* o4 = reinterpret_cast<float4*>(out) + (size_t)row * 4;
#pragma unroll
  for (int i = 0; i < 4; ++i) o4[i] = ov[i];
  out[OFF_IDX + row] = (float)idx;
  return lsum;
}

__global__ __launch_bounds__(BLOCK, 2)
void vq_main(const float* __restrict__ z, const float* __restrict__ emb,
             float* __restrict__ out, float* __restrict__ partials) {
  __shared__ float4 se[K * 4];       // 64 KB codebook
  __shared__ float  se2[K];          // 4 KB ||e_k||^2
  __shared__ float  sbest[4][RPB];   // 2 KB per-wave argmin partials
  __shared__ int    sidx[4][RPB];    // 2 KB

  const int t = threadIdx.x;
  const int lane = t & 63;
  const int w = t >> 6;                       // wave id == k-quarter
  const int rowbase = blockIdx.x * RPB;

  // ---- stage codebook: dense float4 copy (coalesced, conflict-free LDS writes) ----
  const float4* g4 = reinterpret_cast<const float4*>(emb);
#pragma unroll
  for (int i = 0; i < 16; ++i) se[t + i * BLOCK] = g4[t + i * BLOCK];

  // ---- e2 from global re-reads (L1/L2 hits; avoids 32-way LDS read conflicts) ----
#pragma unroll
  for (int n = 0; n < 4; ++n) {
    const int k = t + n * BLOCK;
    float4 e[4];
#pragma unroll
    for (int i = 0; i < 4; ++i) e[i] = g4[k * 4 + i];
    se2[k] = np_sumsq16(reinterpret_cast<const float*>(e));
  }

  // ---- my two z rows + np-bitwise z2 ----
  const int r0 = rowbase + lane;
  const int r1 = r0 + 64;
  const float4* z4 = reinterpret_cast<const float4*>(z);
  float4 za[4], zb[4];
#pragma unroll
  for (int i = 0; i < 4; ++i) { za[i] = z4[(size_t)r0 * 4 + i]; zb[i] = z4[(size_t)r1 * 4 + i]; }
  const float z2a = np_sumsq16(reinterpret_cast<const float*>(za));
  const float z2b = np_sumsq16(reinterpret_cast<const float*>(zb));

  __syncthreads();

  // ---- main loop: this wave's K-quarter; LDS reads are wave-uniform (broadcast) ----
  float besta = __builtin_inff(), bestb = __builtin_inff();
  int bia = 0, bib = 0;
  const int k0 = w * (K / 4);
#pragma unroll 4
  for (int kk = 0; kk < K / 4; ++kk) {
    const int k = k0 + kk;
    const float4 e0 = se[k * 4 + 0];
    const float4 e1 = se[k * 4 + 1];
    const float4 e2 = se[k * 4 + 2];
    const float4 e3 = se[k * 4 + 3];
    const float  e2k = se2[k];
    dist_update(za, e0, e1, e2, e3, z2a, e2k, k, besta, bia);
    dist_update(zb, e0, e1, e2, e3, z2b, e2k, k, bestb, bib);
  }

  sbest[w][lane] = besta;      sidx[w][lane] = bia;
  sbest[w][lane + 64] = bestb; sidx[w][lane + 64] = bib;
  __syncthreads();

  if (w == 0) {
    // merge 4 k-quarters; ascending quarter order + lower-index tie rule == np.argmin(first)
    float b0 = sbest[0][lane];      int i0 = sidx[0][lane];
    float b1 = sbest[0][lane + 64]; int i1 = sidx[0][lane + 64];
#pragma unroll
    for (int q = 1; q < 4; ++q) {
      const float ob0 = sbest[q][lane];      const int oi0 = sidx[q][lane];
      const float ob1 = sbest[q][lane + 64]; const int oi1 = sidx[q][lane + 64];
      if (ob0 < b0 || (ob0 == b0 && oi0 < i0)) { b0 = ob0; i0 = oi0; }
      if (ob1 < b1 || (ob1 == b1 && oi1 < i1)) { b1 = ob1; i1 = oi1; }
    }
    float lsum = finalize_row(za, se, i0, r0, out);
    lsum += finalize_row(zb, se, i1, r1, out);
    // deterministic wave reduction, one partial per block
#pragma unroll
    for (int off = 32; off > 0; off >>= 1) lsum += __shfl_down(lsum, off);
    if (lane == 0) partials[blockIdx.x] = lsum;
  }
}

__global__ __launch_bounds__(BLOCK)
void vq_fin(const float* __restrict__ partials, float* __restrict__ out) {
  const int t = threadIdx.x;
  float v = partials[t] + partials[t + BLOCK];
#pragma unroll
  for (int off = 32; off > 0; off >>= 1) v += __shfl_down(v, off);
  __shared__ float s[4];
  if ((t & 63) == 0) s[t >> 6] = v;
  __syncthreads();
  if (t == 0) {
    const float S = (s[0] + s[1]) + (s[2] + s[3]);
    const float m = S / 1048576.0f;          // np.mean
    out[OFF_LOSS] = 1.25f * m;               // m + 0.25*m  == R(1.25*m)
  }
}

extern "C" void kernel_launch(void* const* d_in, const int* in_sizes, int n_in,
                              void* d_out, int out_size, void* d_ws, size_t ws_size,
                              hipStream_t stream) {
  const float* z   = reinterpret_cast<const float*>(d_in[0]);
  const float* emb = reinterpret_cast<const float*>(d_in[1]);
  float* out       = reinterpret_cast<float*>(d_out);
  float* partials  = reinterpret_cast<float*>(d_ws);   // 512 floats scratch
  vq_main<<<NBLK, BLOCK, 0, stream>>>(z, emb, out, partials);
  vq_fin<<<1, BLOCK, 0, stream>>>(partials, out);
}